// Round 7
// baseline (525.723 us; speedup 1.0000x reference)
//
#include <hip/hip_runtime.h>
#include <hip/hip_cooperative_groups.h>
#include <math.h>

namespace cg = cooperative_groups;

#define NN 50000
#define EE 600000
#define DD 128
#define GG 64
#define NCLS 10
#define PCHUNK 128
#define SCHUNK 1024
#define NCHUNK ((NN + SCHUNK - 1) / SCHUNK)   // 49

typedef __attribute__((ext_vector_type(8))) __bf16 bf16x8;
typedef __attribute__((ext_vector_type(8))) unsigned short u16x8;
typedef __attribute__((ext_vector_type(4))) float f32x4;

__device__ __forceinline__ unsigned short f2bf(float f) {
    unsigned int u = __float_as_uint(f);
    u += 0x7fff + ((u >> 16) & 1);     // round-to-nearest-even
    return (unsigned short)(u >> 16);
}

__device__ __forceinline__ float bf2f(unsigned short h) {
    return __uint_as_float(((unsigned int)h) << 16);
}

// ---------------- cooperative CSR build + weight convert + zeroing ----------
// 256 blocks x 1024 threads (1 block/CU, co-resident). Replaces 2 memsets +
// hist + scan1/2/3 + fill + wt  (8 launches -> 1).

__global__ __launch_bounds__(1024) void csr_coop(
    const int* __restrict__ src, const int* __restrict__ dst,
    const float* __restrict__ wq, const float* __restrict__ wk,
    const float* __restrict__ wv, const float* __restrict__ ws,
    int* __restrict__ cnt, int* __restrict__ indptr, int* __restrict__ cursor,
    int* __restrict__ esrc, int* __restrict__ csum,
    unsigned short* __restrict__ wt, float* __restrict__ gsum) {
    cg::grid_group grid = cg::this_grid();
    __shared__ int wsum[16];
    const int TOT = 256 * 1024;
    int t = threadIdx.x;
    int tid = blockIdx.x * 1024 + t;
    int lane = t & 63, wid = t >> 6;

    // phase 0: zero cnt + gsum/gcnt, convert weights to bf16 n-major
    for (int i = tid; i < NN; i += TOT) cnt[i] = 0;
    if (tid < GG * DD + GG) gsum[tid] = 0.f;
    for (int i = tid; i < 2 * 4 * 16384; i += TOT) {
        int k = i & 127;
        int n = (i >> 7) & 127;
        int lm = i >> 14;
        int l = lm >> 2, m = lm & 3;
        const float* w = (m == 0) ? wq : (m == 1) ? wk : (m == 2) ? wv : ws;
        wt[i] = f2bf(w[l * 16384 + k * 128 + n]);
    }
    grid.sync();

    // phase 1: histogram of dst
    for (int i = tid; i < EE; i += TOT) atomicAdd(&cnt[dst[i]], 1);
    grid.sync();

    // phase 2: block-local exclusive scan (blocks 0..NCHUNK-1), result in regs
    int myexcl = 0, idx = NN;   // idx >= NN => inactive in phase 3b
    if (blockIdx.x < NCHUNK) {
        idx = blockIdx.x * SCHUNK + t;
        int v = (idx < NN) ? cnt[idx] : 0;
        int x = v;
        #pragma unroll
        for (int off = 1; off < 64; off <<= 1) {
            int y = __shfl_up(x, off);
            if (lane >= off) x += y;
        }
        if (lane == 63) wsum[wid] = x;
        __syncthreads();
        if (wid == 0) {
            int wv_ = (lane < 16) ? wsum[lane] : 0;
            int xs = wv_;
            #pragma unroll
            for (int off = 1; off < 16; off <<= 1) {
                int y = __shfl_up(xs, off);
                if (lane >= off) xs += y;
            }
            if (lane < 16) wsum[lane] = xs - wv_;   // exclusive wave prefix
        }
        __syncthreads();
        myexcl = wsum[wid] + x - v;
        if (t == 1023) csum[blockIdx.x] = wsum[15] + x;   // chunk total
    }
    grid.sync();

    // phase 3a: exclusive scan of the NCHUNK chunk totals (block 0, wave 0)
    if (blockIdx.x == 0 && t < 64) {
        int v = (t < NCHUNK) ? csum[t] : 0;
        int x = v;
        #pragma unroll
        for (int off = 1; off < 64; off <<= 1) {
            int y = __shfl_up(x, off);
            if (lane >= off) x += y;
        }
        if (t < NCHUNK) csum[t] = x - v;
    }
    grid.sync();

    // phase 3b: write indptr + cursor
    if (blockIdx.x < NCHUNK && idx < NN) {
        int val = myexcl + csum[blockIdx.x];
        indptr[idx] = val;
        cursor[idx] = val;
    }
    if (tid == 0) indptr[NN] = EE;
    grid.sync();

    // phase 4: scatter src ids into CSR order
    for (int i = tid; i < EE; i += TOT) {
        int pos = atomicAdd(&cursor[dst[i]], 1);
        esrc[pos] = src[i];
    }
}

// ---------------- bf16 MFMA QKVS GEMM: 64-row strip, all 4 mats per block ----
// (256,2): 256-VGPR budget so the 16 B-fragment loads stay register-resident
// and in flight (at the default budget the compiler serialized them - R6 was
// latency-bound at VGPR_Count=64).

__global__ __launch_bounds__(256, 2) void gemm_mfma(
    const float* __restrict__ x,
    const unsigned short* __restrict__ wt,      // [4][128][128] bf16, n-major
    const float* __restrict__ bq, const float* __restrict__ bk,
    const float* __restrict__ bv, const float* __restrict__ bs,
    float* __restrict__ q, unsigned short* __restrict__ kb16,
    unsigned short* __restrict__ vb16, float* __restrict__ s) {
    __shared__ __align__(16) unsigned short As[64 * 136];

    int t = threadIdx.x;
    int row0 = blockIdx.x * 64;

    int kg = t & 15, rb = t >> 4;
    #pragma unroll
    for (int i = 0; i < 4; ++i) {
        int row = rb + i * 16;
        int grow = row0 + row;
        float4 f0 = {0.f, 0.f, 0.f, 0.f}, f1 = {0.f, 0.f, 0.f, 0.f};
        if (grow < NN) {
            const float* p = x + (size_t)grow * DD + kg * 8;
            f0 = *(const float4*)p;
            f1 = *(const float4*)(p + 4);
        }
        u16x8 a8;
        a8[0] = f2bf(f0.x); a8[1] = f2bf(f0.y); a8[2] = f2bf(f0.z); a8[3] = f2bf(f0.w);
        a8[4] = f2bf(f1.x); a8[5] = f2bf(f1.y); a8[6] = f2bf(f1.z); a8[7] = f2bf(f1.w);
        *(u16x8*)&As[row * 136 + kg * 8] = a8;
    }
    __syncthreads();

    int lane = t & 63;
    int wave = t >> 6;
    int wm2 = wave >> 1, wn2 = wave & 1;
    int lr = lane & 15, quad = lane >> 4;

    #pragma unroll
    for (int mat = 0; mat < 4; ++mat) {
        const unsigned short* wm_ = wt + mat * 16384;
        const float* bias = (mat == 0) ? bq : (mat == 1) ? bk : (mat == 2) ? bv : bs;

        bf16x8 bfr[4][4];
        #pragma unroll
        for (int ks = 0; ks < 4; ++ks)
            #pragma unroll
            for (int tn = 0; tn < 4; ++tn)
                bfr[ks][tn] = *(const bf16x8*)(wm_ + (wn2 * 64 + tn * 16 + lr) * 128
                                                    + ks * 32 + quad * 8);

        f32x4 acc[2][4];
        #pragma unroll
        for (int a = 0; a < 2; ++a)
            #pragma unroll
            for (int b = 0; b < 4; ++b)
                acc[a][b] = (f32x4){0.f, 0.f, 0.f, 0.f};

        #pragma unroll
        for (int ks = 0; ks < 4; ++ks) {
            bf16x8 af[2];
            #pragma unroll
            for (int tm = 0; tm < 2; ++tm)
                af[tm] = *(const bf16x8*)&As[(wm2 * 32 + tm * 16 + lr) * 136
                                             + ks * 32 + quad * 8];
            #pragma unroll
            for (int tm = 0; tm < 2; ++tm)
                #pragma unroll
                for (int tn = 0; tn < 4; ++tn)
                    acc[tm][tn] = __builtin_amdgcn_mfma_f32_16x16x32_bf16(
                        af[tm], bfr[ks][tn], acc[tm][tn], 0, 0, 0);
        }

        // C/D layout: col = lane&15, row = quad*4 + reg
        if (mat == 0 || mat == 3) {
            float* outp = (mat == 0) ? q : s;
            #pragma unroll
            for (int tn = 0; tn < 4; ++tn) {
                int col = wn2 * 64 + tn * 16 + lr;
                float bv_ = bias[col];
                #pragma unroll
                for (int tm = 0; tm < 2; ++tm) {
                    int nb = row0 + wm2 * 32 + tm * 16 + quad * 4;
                    #pragma unroll
                    for (int r = 0; r < 4; ++r) {
                        int node = nb + r;
                        if (node < NN)
                            outp[(size_t)node * DD + col] = acc[tm][tn][r] + bv_;
                    }
                }
            }
        } else {
            unsigned short* outp = (mat == 1) ? kb16 : vb16;
            #pragma unroll
            for (int tn = 0; tn < 4; ++tn) {
                int col = wn2 * 64 + tn * 16 + lr;
                float bv_ = bias[col];
                #pragma unroll
                for (int tm = 0; tm < 2; ++tm) {
                    int nb = row0 + wm2 * 32 + tm * 16 + quad * 4;
                    #pragma unroll
                    for (int r = 0; r < 4; ++r) {
                        int node = nb + r;
                        if (node < NN)
                            outp[(size_t)node * DD + col] = f2bf(acc[tm][tn][r] + bv_);
                    }
                }
            }
        }
    }
}

// ---------------- attention: 4 edges/wave via 16-lane subgroups ----------------

__global__ __launch_bounds__(256) void attn_kernel(
    const float* __restrict__ q, const unsigned short* __restrict__ kb16,
    const unsigned short* __restrict__ vb16, const float* __restrict__ s,
    const int* __restrict__ indptr, const int* __restrict__ esrc,
    float* __restrict__ hout, int n) {
    int node = (int)((blockIdx.x * blockDim.x + threadIdx.x) >> 6);
    int lane = threadIdx.x & 63;
    if (node >= n) return;
    int g = lane >> 4, j = lane & 15;

    const float* qp = q + (size_t)node * DD + j * 8;
    float4 q0 = *(const float4*)qp;
    float4 q1 = *(const float4*)(qp + 4);

    int beg = indptr[node], end = indptr[node + 1];

    float m = -3.0e38f, den = 0.f;
    float acc[8];
    #pragma unroll
    for (int c = 0; c < 8; ++c) acc[c] = 0.f;

    for (int e = beg + g; e < end; e += 4) {
        int sidx = esrc[e];
        u16x8 k8 = *(const u16x8*)(kb16 + (size_t)sidx * DD + j * 8);
        u16x8 v8 = *(const u16x8*)(vb16 + (size_t)sidx * DD + j * 8);
        float p;
        p  = q0.x * bf2f(k8[0]);
        p  = fmaf(q0.y, bf2f(k8[1]), p);
        p  = fmaf(q0.z, bf2f(k8[2]), p);
        p  = fmaf(q0.w, bf2f(k8[3]), p);
        p  = fmaf(q1.x, bf2f(k8[4]), p);
        p  = fmaf(q1.y, bf2f(k8[5]), p);
        p  = fmaf(q1.z, bf2f(k8[6]), p);
        p  = fmaf(q1.w, bf2f(k8[7]), p);
        p += __shfl_xor(p, 8);
        p += __shfl_xor(p, 4);
        p += __shfl_xor(p, 2);
        p += __shfl_xor(p, 1);
        float score = p * 0.088388347648318447f;   // 1/sqrt(128)
        float mn = fmaxf(m, score);
        float scale = __expf(m - mn);
        float pe = __expf(score - mn);
        den = den * scale + pe;
        #pragma unroll
        for (int c = 0; c < 8; ++c)
            acc[c] = fmaf(acc[c], scale, pe * bf2f(v8[c]));
        m = mn;
    }

    float mo = __shfl_xor(m, 16);
    float m2 = fmaxf(m, mo);
    mo = __shfl_xor(m2, 32);
    float mf = fmaxf(m2, mo);
    float sc = __expf(m - mf);
    den *= sc;
    den += __shfl_xor(den, 16);
    den += __shfl_xor(den, 32);
    #pragma unroll
    for (int c = 0; c < 8; ++c) {
        float a = acc[c] * sc;
        a += __shfl_xor(a, 16);
        a += __shfl_xor(a, 32);
        acc[c] = a;
    }
    float inv = den > 0.f ? 1.0f / den : 0.f;
    if (g == 0) {
        const float* sp = s + (size_t)node * DD + j * 8;
        float4 s0 = *(const float4*)sp;
        float4 s1 = *(const float4*)(sp + 4);
        float4 o0, o1;
        o0.x = fmaxf(fmaf(acc[0], inv, s0.x), 0.f);
        o0.y = fmaxf(fmaf(acc[1], inv, s0.y), 0.f);
        o0.z = fmaxf(fmaf(acc[2], inv, s0.z), 0.f);
        o0.w = fmaxf(fmaf(acc[3], inv, s0.w), 0.f);
        o1.x = fmaxf(fmaf(acc[4], inv, s1.x), 0.f);
        o1.y = fmaxf(fmaf(acc[5], inv, s1.y), 0.f);
        o1.z = fmaxf(fmaf(acc[6], inv, s1.z), 0.f);
        o1.w = fmaxf(fmaf(acc[7], inv, s1.w), 0.f);
        float* op = hout + (size_t)node * DD + j * 8;
        *(float4*)op = o0;
        *(float4*)(op + 4) = o1;
    }
}

// ---------------- global mean pool: segmented running sum ----------------

__global__ __launch_bounds__(128) void pool_kernel(const float* __restrict__ h,
                                                   const int* __restrict__ batch,
                                                   float* __restrict__ gsum,
                                                   float* __restrict__ gcnt, int n) {
    __shared__ int bsh[PCHUNK];
    int t = threadIdx.x;
    int node0 = blockIdx.x * PCHUNK;
    int nnodes = min(PCHUNK, n - node0);
    if (t < nnodes) bsh[t] = batch[node0 + t];
    __syncthreads();

    int cur = bsh[0];
    float acc = 0.f;
    int cnt = 0;
    int j = 0;
    for (; j + 4 <= nnodes; j += 4) {
        float v0 = h[(size_t)(node0 + j + 0) * DD + t];
        float v1 = h[(size_t)(node0 + j + 1) * DD + t];
        float v2 = h[(size_t)(node0 + j + 2) * DD + t];
        float v3 = h[(size_t)(node0 + j + 3) * DD + t];
        int g0 = bsh[j + 0], g1 = bsh[j + 1], g2 = bsh[j + 2], g3 = bsh[j + 3];
        #pragma unroll
        for (int u = 0; u < 4; ++u) {
            int g = (u == 0) ? g0 : (u == 1) ? g1 : (u == 2) ? g2 : g3;
            float val = (u == 0) ? v0 : (u == 1) ? v1 : (u == 2) ? v2 : v3;
            if (g != cur) {
                atomicAdd(&gsum[cur * DD + t], acc);
                if (t == 0) atomicAdd(&gcnt[cur], (float)cnt);
                acc = 0.f; cnt = 0; cur = g;
            }
            acc += val; ++cnt;
        }
    }
    for (; j < nnodes; ++j) {
        int g = bsh[j];
        float val = h[(size_t)(node0 + j) * DD + t];
        if (g != cur) {
            atomicAdd(&gsum[cur * DD + t], acc);
            if (t == 0) atomicAdd(&gcnt[cur], (float)cnt);
            acc = 0.f; cnt = 0; cur = g;
        }
        acc += val; ++cnt;
    }
    if (cnt > 0) {
        atomicAdd(&gsum[cur * DD + t], acc);
        if (t == 0) atomicAdd(&gcnt[cur], (float)cnt);
    }
}

// ---------------- FC + log_softmax ----------------

__global__ __launch_bounds__(64) void head_kernel(
    const float* __restrict__ gsum, const float* __restrict__ gcnt,
    const float* __restrict__ wfc, const float* __restrict__ bfc,
    float* __restrict__ out) {
    int g = blockIdx.x;
    int lane = threadIdx.x;
    float cnt = fmaxf(gcnt[g], 1.0f);
    float inv = 1.0f / cnt;
    float p0 = gsum[g * DD + lane] * inv;
    float p1 = gsum[g * DD + lane + 64] * inv;
    __shared__ float logits[NCLS];
    for (int c = 0; c < NCLS; ++c) {
        float partial = p0 * wfc[lane * NCLS + c] + p1 * wfc[(lane + 64) * NCLS + c];
        partial += __shfl_xor(partial, 32);
        partial += __shfl_xor(partial, 16);
        partial += __shfl_xor(partial, 8);
        partial += __shfl_xor(partial, 4);
        partial += __shfl_xor(partial, 2);
        partial += __shfl_xor(partial, 1);
        if (lane == 0) logits[c] = partial + bfc[c];
    }
    __syncthreads();
    if (lane == 0) {
        float mx = logits[0];
        for (int c = 1; c < NCLS; ++c) mx = fmaxf(mx, logits[c]);
        float sum = 0.f;
        for (int c = 0; c < NCLS; ++c) sum += expf(logits[c] - mx);
        float lse = mx + logf(sum);
        for (int c = 0; c < NCLS; ++c) out[g * NCLS + c] = logits[c] - lse;
    }
}

// ---------------- launch ----------------

extern "C" void kernel_launch(void* const* d_in, const int* in_sizes, int n_in,
                              void* d_out, int out_size, void* d_ws, size_t ws_size,
                              hipStream_t stream) {
    const float* x     = (const float*)d_in[0];
    const int*   ei    = (const int*)d_in[1];
    const int*   batch = (const int*)d_in[2];
    const float* Wq = (const float*)d_in[3];
    const float* bq = (const float*)d_in[4];
    const float* Wk = (const float*)d_in[5];
    const float* bk = (const float*)d_in[6];
    const float* Wv = (const float*)d_in[7];
    const float* bv = (const float*)d_in[8];
    const float* Ws = (const float*)d_in[9];
    const float* bs = (const float*)d_in[10];
    const float* Wfc = (const float*)d_in[11];
    const float* bfc = (const float*)d_in[12];
    float* out = (float*)d_out;

    const size_t ND = (size_t)NN * DD;
    float* hbuf = (float*)d_ws;
    float* qb = hbuf + ND;
    float* sb = qb + ND;
    unsigned short* kb16 = (unsigned short*)(sb + ND);
    unsigned short* vb16 = kb16 + ND;
    unsigned short* wt = vb16 + ND;                 // [2][4][128][128] bf16
    int* cnt    = (int*)(wt + 2 * 4 * 16384);
    int* indptr = cnt + NN;
    int* cursor = indptr + NN + 1;
    int* esrc   = cursor + NN;
    int* csum   = esrc + EE;
    float* gsum = (float*)(csum + NCHUNK);
    float* gcnt = gsum + GG * DD;

    const int* src = ei;
    const int* dst = ei + EE;

    {
        const int* srcp = src; const int* dstp = dst;
        const float* wqp = Wq; const float* wkp = Wk;
        const float* wvp = Wv; const float* wsp = Ws;
        int* cntp = cnt; int* indptrp = indptr; int* cursorp = cursor;
        int* esrcp = esrc; int* csump = csum;
        unsigned short* wtp = wt; float* gsump = gsum;
        void* args[] = {&srcp, &dstp, &wqp, &wkp, &wvp, &wsp,
                        &cntp, &indptrp, &cursorp, &esrcp, &csump, &wtp, &gsump};
        hipLaunchCooperativeKernel(reinterpret_cast<void*>(csr_coop),
                                   dim3(256), dim3(1024), args, 0, stream);
    }

    for (int l = 0; l < 2; ++l) {
        const float* hin = (l == 0) ? x : hbuf;
        size_t bo = (size_t)l * DD;
        gemm_mfma<<<(NN + 63) / 64, 256, 0, stream>>>(
            hin, wt + (size_t)l * 4 * 16384,
            bq + bo, bk + bo, bv + bo, bs + bo,
            qb, kb16, vb16, sb);
        attn_kernel<<<(NN + 3) / 4, 256, 0, stream>>>(
            qb, kb16, vb16, sb, indptr, esrc, hbuf, NN);
    }

    pool_kernel<<<(NN + PCHUNK - 1) / PCHUNK, 128, 0, stream>>>(hbuf, batch, gsum, gcnt, NN);
    head_kernel<<<GG, 64, 0, stream>>>(gsum, gcnt, Wfc, bfc, out);
}

// Round 8
// 379.135 us; speedup vs baseline: 1.3866x; 1.3866x over previous
//
#include <hip/hip_runtime.h>
#include <math.h>

#define NN 50000
#define EE 600000
#define DD 128
#define GG 64
#define NCLS 10
#define PCHUNK 128
#define SCHUNK 1024
#define NCHUNK ((NN + SCHUNK - 1) / SCHUNK)

typedef __attribute__((ext_vector_type(8))) __bf16 bf16x8;
typedef __attribute__((ext_vector_type(8))) unsigned short u16x8;
typedef __attribute__((ext_vector_type(4))) float f32x4;

__device__ __forceinline__ unsigned short f2bf(float f) {
    unsigned int u = __float_as_uint(f);
    u += 0x7fff + ((u >> 16) & 1);     // round-to-nearest-even
    return (unsigned short)(u >> 16);
}

__device__ __forceinline__ float bf2f(unsigned short h) {
    return __uint_as_float(((unsigned int)h) << 16);
}

// ---------------- CSR build (split chain: beats grid.sync on MI355X, R7) ----

__global__ void hist_kernel(const int* __restrict__ dst, int* __restrict__ cnt, int e) {
    int i = blockIdx.x * blockDim.x + threadIdx.x;
    if (i < e) atomicAdd(&cnt[dst[i]], 1);
}

__global__ __launch_bounds__(1024) void scan1_kernel(const int* __restrict__ cnt,
                                                     int* __restrict__ lexcl,
                                                     int* __restrict__ csum, int n) {
    __shared__ int wsum[16];
    int tid = threadIdx.x;
    int lane = tid & 63, wid = tid >> 6;
    int i = blockIdx.x * SCHUNK + tid;
    int v = (i < n) ? cnt[i] : 0;
    int x = v;
    #pragma unroll
    for (int off = 1; off < 64; off <<= 1) {
        int y = __shfl_up(x, off);
        if (lane >= off) x += y;
    }
    if (lane == 63) wsum[wid] = x;
    __syncthreads();
    if (wid == 0) {
        int ws = (lane < 16) ? wsum[lane] : 0;
        int xs = ws;
        #pragma unroll
        for (int off = 1; off < 16; off <<= 1) {
            int y = __shfl_up(xs, off);
            if (lane >= off) xs += y;
        }
        if (lane < 16) wsum[lane] = xs - ws;
    }
    __syncthreads();
    if (i < n) lexcl[i] = wsum[wid] + x - v;
    if (tid == 1023) csum[blockIdx.x] = wsum[15] + x;
}

__global__ __launch_bounds__(64) void scan2_kernel(int* __restrict__ csum, int nchunk) {
    int lane = threadIdx.x;
    int v = (lane < nchunk) ? csum[lane] : 0;
    int x = v;
    #pragma unroll
    for (int off = 1; off < 64; off <<= 1) {
        int y = __shfl_up(x, off);
        if (lane >= off) x += y;
    }
    if (lane < nchunk) csum[lane] = x - v;
}

__global__ __launch_bounds__(1024) void scan3_kernel(const int* __restrict__ lexcl,
                                                     const int* __restrict__ csum,
                                                     int* __restrict__ indptr,
                                                     int* __restrict__ cursor,
                                                     int n, int total) {
    int i = blockIdx.x * SCHUNK + threadIdx.x;
    if (i < n) {
        int val = lexcl[i] + csum[blockIdx.x];
        indptr[i] = val;
        cursor[i] = val;
    }
    if (i == 0) indptr[n] = total;
}

__global__ void fill_kernel(const int* __restrict__ src, const int* __restrict__ dst,
                            int* __restrict__ cursor, int* __restrict__ esrc, int e) {
    int i = blockIdx.x * blockDim.x + threadIdx.x;
    if (i < e) {
        int pos = atomicAdd(&cursor[dst[i]], 1);
        esrc[pos] = src[i];
    }
}

// ---------------- weight pre-transpose + bf16 convert ----------------

__global__ void wt_kernel(const float* __restrict__ wq, const float* __restrict__ wk,
                          const float* __restrict__ wv, const float* __restrict__ ws,
                          unsigned short* __restrict__ wt) {
    int idx = blockIdx.x * 256 + threadIdx.x;
    int k = idx & 127;
    int n = (idx >> 7) & 127;
    int lm = idx >> 14;
    int l = lm >> 2, m = lm & 3;
    const float* w = (m == 0) ? wq : (m == 1) ? wk : (m == 2) ? wv : ws;
    wt[idx] = f2bf(w[l * 16384 + k * 128 + n]);
}

// ---------------- bf16 MFMA QKVS GEMM: 64-row strip, all 4 mats per block ----
// (256,2): 256-VGPR budget so the 16 B-fragment loads stay register-resident
// (at default budget the compiler allotted 64 VGPR and serialized them - R6).

__global__ __launch_bounds__(256, 2) void gemm_mfma(
    const float* __restrict__ x,
    const unsigned short* __restrict__ wt,      // [4][128][128] bf16, n-major
    const float* __restrict__ bq, const float* __restrict__ bk,
    const float* __restrict__ bv, const float* __restrict__ bs,
    float* __restrict__ q, unsigned short* __restrict__ kb16,
    unsigned short* __restrict__ vb16, float* __restrict__ s) {
    __shared__ __align__(16) unsigned short As[64 * 136];

    int t = threadIdx.x;
    int row0 = blockIdx.x * 64;

    int kg = t & 15, rb = t >> 4;
    #pragma unroll
    for (int i = 0; i < 4; ++i) {
        int row = rb + i * 16;
        int grow = row0 + row;
        float4 f0 = {0.f, 0.f, 0.f, 0.f}, f1 = {0.f, 0.f, 0.f, 0.f};
        if (grow < NN) {
            const float* p = x + (size_t)grow * DD + kg * 8;
            f0 = *(const float4*)p;
            f1 = *(const float4*)(p + 4);
        }
        u16x8 a8;
        a8[0] = f2bf(f0.x); a8[1] = f2bf(f0.y); a8[2] = f2bf(f0.z); a8[3] = f2bf(f0.w);
        a8[4] = f2bf(f1.x); a8[5] = f2bf(f1.y); a8[6] = f2bf(f1.z); a8[7] = f2bf(f1.w);
        *(u16x8*)&As[row * 136 + kg * 8] = a8;
    }
    __syncthreads();

    int lane = t & 63;
    int wave = t >> 6;
    int wm2 = wave >> 1, wn2 = wave & 1;
    int lr = lane & 15, quad = lane >> 4;

    #pragma unroll
    for (int mat = 0; mat < 4; ++mat) {
        const unsigned short* wm_ = wt + mat * 16384;
        const float* bias = (mat == 0) ? bq : (mat == 1) ? bk : (mat == 2) ? bv : bs;

        bf16x8 bfr[4][4];
        #pragma unroll
        for (int ks = 0; ks < 4; ++ks)
            #pragma unroll
            for (int tn = 0; tn < 4; ++tn)
                bfr[ks][tn] = *(const bf16x8*)(wm_ + (wn2 * 64 + tn * 16 + lr) * 128
                                                    + ks * 32 + quad * 8);

        f32x4 acc[2][4];
        #pragma unroll
        for (int a = 0; a < 2; ++a)
            #pragma unroll
            for (int b = 0; b < 4; ++b)
                acc[a][b] = (f32x4){0.f, 0.f, 0.f, 0.f};

        #pragma unroll
        for (int ks = 0; ks < 4; ++ks) {
            bf16x8 af[2];
            #pragma unroll
            for (int tm = 0; tm < 2; ++tm)
                af[tm] = *(const bf16x8*)&As[(wm2 * 32 + tm * 16 + lr) * 136
                                             + ks * 32 + quad * 8];
            #pragma unroll
            for (int tm = 0; tm < 2; ++tm)
                #pragma unroll
                for (int tn = 0; tn < 4; ++tn)
                    acc[tm][tn] = __builtin_amdgcn_mfma_f32_16x16x32_bf16(
                        af[tm], bfr[ks][tn], acc[tm][tn], 0, 0, 0);
        }

        // C/D layout: col = lane&15, row = quad*4 + reg
        if (mat == 0 || mat == 3) {
            float* outp = (mat == 0) ? q : s;
            #pragma unroll
            for (int tn = 0; tn < 4; ++tn) {
                int col = wn2 * 64 + tn * 16 + lr;
                float bv_ = bias[col];
                #pragma unroll
                for (int tm = 0; tm < 2; ++tm) {
                    int nb = row0 + wm2 * 32 + tm * 16 + quad * 4;
                    #pragma unroll
                    for (int r = 0; r < 4; ++r) {
                        int node = nb + r;
                        if (node < NN)
                            outp[(size_t)node * DD + col] = acc[tm][tn][r] + bv_;
                    }
                }
            }
        } else {
            unsigned short* outp = (mat == 1) ? kb16 : vb16;
            #pragma unroll
            for (int tn = 0; tn < 4; ++tn) {
                int col = wn2 * 64 + tn * 16 + lr;
                float bv_ = bias[col];
                #pragma unroll
                for (int tm = 0; tm < 2; ++tm) {
                    int nb = row0 + wm2 * 32 + tm * 16 + quad * 4;
                    #pragma unroll
                    for (int r = 0; r < 4; ++r) {
                        int node = nb + r;
                        if (node < NN)
                            outp[(size_t)node * DD + col] = f2bf(acc[tm][tn][r] + bv_);
                    }
                }
            }
        }
    }
}

// ---------------- attention: 4 edges/wave via 16-lane subgroups ----------------

__global__ __launch_bounds__(256) void attn_kernel(
    const float* __restrict__ q, const unsigned short* __restrict__ kb16,
    const unsigned short* __restrict__ vb16, const float* __restrict__ s,
    const int* __restrict__ indptr, const int* __restrict__ esrc,
    float* __restrict__ hout, int n) {
    int node = (int)((blockIdx.x * blockDim.x + threadIdx.x) >> 6);
    int lane = threadIdx.x & 63;
    if (node >= n) return;
    int g = lane >> 4, j = lane & 15;

    const float* qp = q + (size_t)node * DD + j * 8;
    float4 q0 = *(const float4*)qp;
    float4 q1 = *(const float4*)(qp + 4);

    int beg = indptr[node], end = indptr[node + 1];

    float m = -3.0e38f, den = 0.f;
    float acc[8];
    #pragma unroll
    for (int c = 0; c < 8; ++c) acc[c] = 0.f;

    for (int e = beg + g; e < end; e += 4) {
        int sidx = esrc[e];
        u16x8 k8 = *(const u16x8*)(kb16 + (size_t)sidx * DD + j * 8);
        u16x8 v8 = *(const u16x8*)(vb16 + (size_t)sidx * DD + j * 8);
        float p;
        p  = q0.x * bf2f(k8[0]);
        p  = fmaf(q0.y, bf2f(k8[1]), p);
        p  = fmaf(q0.z, bf2f(k8[2]), p);
        p  = fmaf(q0.w, bf2f(k8[3]), p);
        p  = fmaf(q1.x, bf2f(k8[4]), p);
        p  = fmaf(q1.y, bf2f(k8[5]), p);
        p  = fmaf(q1.z, bf2f(k8[6]), p);
        p  = fmaf(q1.w, bf2f(k8[7]), p);
        p += __shfl_xor(p, 8);
        p += __shfl_xor(p, 4);
        p += __shfl_xor(p, 2);
        p += __shfl_xor(p, 1);
        float score = p * 0.088388347648318447f;   // 1/sqrt(128)
        float mn = fmaxf(m, score);
        float scale = __expf(m - mn);
        float pe = __expf(score - mn);
        den = den * scale + pe;
        #pragma unroll
        for (int c = 0; c < 8; ++c)
            acc[c] = fmaf(acc[c], scale, pe * bf2f(v8[c]));
        m = mn;
    }

    float mo = __shfl_xor(m, 16);
    float m2 = fmaxf(m, mo);
    mo = __shfl_xor(m2, 32);
    float mf = fmaxf(m2, mo);
    float sc = __expf(m - mf);
    den *= sc;
    den += __shfl_xor(den, 16);
    den += __shfl_xor(den, 32);
    #pragma unroll
    for (int c = 0; c < 8; ++c) {
        float a = acc[c] * sc;
        a += __shfl_xor(a, 16);
        a += __shfl_xor(a, 32);
        acc[c] = a;
    }
    float inv = den > 0.f ? 1.0f / den : 0.f;
    if (g == 0) {
        const float* sp = s + (size_t)node * DD + j * 8;
        float4 s0 = *(const float4*)sp;
        float4 s1 = *(const float4*)(sp + 4);
        float4 o0, o1;
        o0.x = fmaxf(fmaf(acc[0], inv, s0.x), 0.f);
        o0.y = fmaxf(fmaf(acc[1], inv, s0.y), 0.f);
        o0.z = fmaxf(fmaf(acc[2], inv, s0.z), 0.f);
        o0.w = fmaxf(fmaf(acc[3], inv, s0.w), 0.f);
        o1.x = fmaxf(fmaf(acc[4], inv, s1.x), 0.f);
        o1.y = fmaxf(fmaf(acc[5], inv, s1.y), 0.f);
        o1.z = fmaxf(fmaf(acc[6], inv, s1.z), 0.f);
        o1.w = fmaxf(fmaf(acc[7], inv, s1.w), 0.f);
        float* op = hout + (size_t)node * DD + j * 8;
        *(float4*)op = o0;
        *(float4*)(op + 4) = o1;
    }
}

// ---------------- global mean pool: segmented running sum ----------------

__global__ __launch_bounds__(128) void pool_kernel(const float* __restrict__ h,
                                                   const int* __restrict__ batch,
                                                   float* __restrict__ gsum,
                                                   float* __restrict__ gcnt, int n) {
    __shared__ int bsh[PCHUNK];
    int t = threadIdx.x;
    int node0 = blockIdx.x * PCHUNK;
    int nnodes = min(PCHUNK, n - node0);
    if (t < nnodes) bsh[t] = batch[node0 + t];
    __syncthreads();

    int cur = bsh[0];
    float acc = 0.f;
    int cnt = 0;
    int j = 0;
    for (; j + 4 <= nnodes; j += 4) {
        float v0 = h[(size_t)(node0 + j + 0) * DD + t];
        float v1 = h[(size_t)(node0 + j + 1) * DD + t];
        float v2 = h[(size_t)(node0 + j + 2) * DD + t];
        float v3 = h[(size_t)(node0 + j + 3) * DD + t];
        int g0 = bsh[j + 0], g1 = bsh[j + 1], g2 = bsh[j + 2], g3 = bsh[j + 3];
        #pragma unroll
        for (int u = 0; u < 4; ++u) {
            int g = (u == 0) ? g0 : (u == 1) ? g1 : (u == 2) ? g2 : g3;
            float val = (u == 0) ? v0 : (u == 1) ? v1 : (u == 2) ? v2 : v3;
            if (g != cur) {
                atomicAdd(&gsum[cur * DD + t], acc);
                if (t == 0) atomicAdd(&gcnt[cur], (float)cnt);
                acc = 0.f; cnt = 0; cur = g;
            }
            acc += val; ++cnt;
        }
    }
    for (; j < nnodes; ++j) {
        int g = bsh[j];
        float val = h[(size_t)(node0 + j) * DD + t];
        if (g != cur) {
            atomicAdd(&gsum[cur * DD + t], acc);
            if (t == 0) atomicAdd(&gcnt[cur], (float)cnt);
            acc = 0.f; cnt = 0; cur = g;
        }
        acc += val; ++cnt;
    }
    if (cnt > 0) {
        atomicAdd(&gsum[cur * DD + t], acc);
        if (t == 0) atomicAdd(&gcnt[cur], (float)cnt);
    }
}

// ---------------- FC + log_softmax ----------------

__global__ __launch_bounds__(64) void head_kernel(
    const float* __restrict__ gsum, const float* __restrict__ gcnt,
    const float* __restrict__ wfc, const float* __restrict__ bfc,
    float* __restrict__ out) {
    int g = blockIdx.x;
    int lane = threadIdx.x;
    float cnt = fmaxf(gcnt[g], 1.0f);
    float inv = 1.0f / cnt;
    float p0 = gsum[g * DD + lane] * inv;
    float p1 = gsum[g * DD + lane + 64] * inv;
    __shared__ float logits[NCLS];
    for (int c = 0; c < NCLS; ++c) {
        float partial = p0 * wfc[lane * NCLS + c] + p1 * wfc[(lane + 64) * NCLS + c];
        partial += __shfl_xor(partial, 32);
        partial += __shfl_xor(partial, 16);
        partial += __shfl_xor(partial, 8);
        partial += __shfl_xor(partial, 4);
        partial += __shfl_xor(partial, 2);
        partial += __shfl_xor(partial, 1);
        if (lane == 0) logits[c] = partial + bfc[c];
    }
    __syncthreads();
    if (lane == 0) {
        float mx = logits[0];
        for (int c = 1; c < NCLS; ++c) mx = fmaxf(mx, logits[c]);
        float sum = 0.f;
        for (int c = 0; c < NCLS; ++c) sum += expf(logits[c] - mx);
        float lse = mx + logf(sum);
        for (int c = 0; c < NCLS; ++c) out[g * NCLS + c] = logits[c] - lse;
    }
}

// ---------------- launch ----------------

extern "C" void kernel_launch(void* const* d_in, const int* in_sizes, int n_in,
                              void* d_out, int out_size, void* d_ws, size_t ws_size,
                              hipStream_t stream) {
    const float* x     = (const float*)d_in[0];
    const int*   ei    = (const int*)d_in[1];
    const int*   batch = (const int*)d_in[2];
    const float* Wq = (const float*)d_in[3];
    const float* bq = (const float*)d_in[4];
    const float* Wk = (const float*)d_in[5];
    const float* bk = (const float*)d_in[6];
    const float* Wv = (const float*)d_in[7];
    const float* bv = (const float*)d_in[8];
    const float* Ws = (const float*)d_in[9];
    const float* bs = (const float*)d_in[10];
    const float* Wfc = (const float*)d_in[11];
    const float* bfc = (const float*)d_in[12];
    float* out = (float*)d_out;

    const size_t ND = (size_t)NN * DD;
    float* hbuf = (float*)d_ws;
    float* qb = hbuf + ND;
    float* sb = qb + ND;
    unsigned short* kb16 = (unsigned short*)(sb + ND);
    unsigned short* vb16 = kb16 + ND;
    unsigned short* wt = vb16 + ND;                 // [2][4][128][128] bf16
    int* cnt    = (int*)(wt + 2 * 4 * 16384);
    int* indptr = cnt + NN;
    int* cursor = indptr + NN + 1;
    int* esrc   = cursor + NN;
    int* lexcl  = esrc + EE;
    int* csum   = lexcl + NN;
    float* gsum = (float*)(csum + NCHUNK);
    float* gcnt = gsum + GG * DD;

    const int* src = ei;
    const int* dst = ei + EE;

    hipMemsetAsync(cnt, 0, NN * sizeof(int), stream);
    hipMemsetAsync(gsum, 0, (GG * DD + GG) * sizeof(float), stream);

    hist_kernel<<<(EE + 255) / 256, 256, 0, stream>>>(dst, cnt, EE);
    scan1_kernel<<<NCHUNK, 1024, 0, stream>>>(cnt, lexcl, csum, NN);
    scan2_kernel<<<1, 64, 0, stream>>>(csum, NCHUNK);
    scan3_kernel<<<NCHUNK, 1024, 0, stream>>>(lexcl, csum, indptr, cursor, NN, EE);
    fill_kernel<<<(EE + 255) / 256, 256, 0, stream>>>(src, dst, cursor, esrc, EE);
    wt_kernel<<<512, 256, 0, stream>>>(Wq, Wk, Wv, Ws, wt);

    for (int l = 0; l < 2; ++l) {
        const float* hin = (l == 0) ? x : hbuf;
        size_t bo = (size_t)l * DD;
        gemm_mfma<<<(NN + 63) / 64, 256, 0, stream>>>(
            hin, wt + (size_t)l * 4 * 16384,
            bq + bo, bk + bo, bv + bo, bs + bo,
            qb, kb16, vb16, sb);
        attn_kernel<<<(NN + 3) / 4, 256, 0, stream>>>(
            qb, kb16, vb16, sb, indptr, esrc, hbuf, NN);
    }

    pool_kernel<<<(NN + PCHUNK - 1) / PCHUNK, 128, 0, stream>>>(hbuf, batch, gsum, gcnt, NN);
    head_kernel<<<GG, 64, 0, stream>>>(gsum, gcnt, Wfc, bfc, out);
}